// Round 4
// baseline (1346.005 us; speedup 1.0000x reference)
//
#include <hip/hip_runtime.h>

#define TSTEPS 48
#define OUT_STEPS 24

typedef __attribute__((ext_vector_type(8))) short bf16x8;
typedef __attribute__((ext_vector_type(4))) float f32x4;
typedef __attribute__((ext_vector_type(2))) float f32x2;
typedef __attribute__((ext_vector_type(4))) unsigned int u32x4;

#define L2E 1.44269504088896340736f

__device__ __forceinline__ f32x2 exp2v(f32x2 a) {
    return (f32x2){__builtin_amdgcn_exp2f(a.x), __builtin_amdgcn_exp2f(a.y)};
}
__device__ __forceinline__ f32x2 rcpv(f32x2 a) {
    return (f32x2){__builtin_amdgcn_rcpf(a.x), __builtin_amdgcn_rcpf(a.y)};
}
__device__ __forceinline__ f32x2 minv(f32x2 a, float m) {
    return (f32x2){__builtin_fminf(a.x, m), __builtin_fminf(a.y, m)};
}

// RNE hi/lo split (weights only; off the hot path).
__device__ __forceinline__ void bf_split(float f, short& hi, short& lo) {
    unsigned u = __builtin_bit_cast(unsigned, f);
    unsigned r = u + 0x7FFFu + ((u >> 16) & 1u);
    unsigned short hb = (unsigned short)(r >> 16);
    float hif = __builtin_bit_cast(float, (unsigned)hb << 16);
    float lof = f - hif;
    unsigned short lb = (unsigned short)(__builtin_bit_cast(unsigned, lof) >> 16);
    hi = (short)hb; lo = (short)lb;
}

// Truncation split of a PAIR, packed to dwords (low half = first value).
// hi error is captured exactly by lo; residual ~2^-17 relative.
__device__ __forceinline__ void bf_split_pair(float f0, float f1,
                                              unsigned& hi, unsigned& lo) {
    unsigned u0 = __builtin_bit_cast(unsigned, f0);
    unsigned u1 = __builtin_bit_cast(unsigned, f1);
    hi = __builtin_amdgcn_perm(u1, u0, 0x07060302u);  // [u0.hi16, u1.hi16]
    float h0 = __builtin_bit_cast(float, u0 & 0xFFFF0000u);
    float h1 = __builtin_bit_cast(float, u1 & 0xFFFF0000u);
    float l0 = f0 - h0, l1 = f1 - h1;
    unsigned v0 = __builtin_bit_cast(unsigned, l0);
    unsigned v1 = __builtin_bit_cast(unsigned, l1);
    lo = __builtin_amdgcn_perm(v1, v0, 0x07060302u);
}

// A-fragments of permuted U^T (hi/lo split) + per-lane Wk/b constants in D order.
// Row permutation: row R=16t+rho <-> gate=(t>>1), unit u=(rho>>2)*8+(t&1)*4+(rho&3).
__device__ __forceinline__ void load_weights(const float* __restrict__ Uk,
                                             const float* __restrict__ Wk,
                                             const float* __restrict__ bv,
                                             bf16x8* Ahi, bf16x8* Alo,
                                             f32x4* wkfr, f32x4* bfr, int LQ, int LC) {
    const int ulo = ((LC >> 2) << 3) + (LC & 3);
#pragma unroll
    for (int t = 0; t < 8; ++t) {
        const int col = (t >> 1) * 32 + ulo + (t & 1) * 4;
        bf16x8 ah, al;
#pragma unroll
        for (int j = 0; j < 8; ++j) {
            float w = Uk[(LQ * 8 + j) * 128 + col];
            short hb, lb; bf_split(w, hb, lb);
            ah[j] = hb; al[j] = lb;
        }
        Ahi[t] = ah; Alo[t] = al;
        const int colb = (t >> 1) * 32 + LQ * 8 + (t & 1) * 4;
#pragma unroll
        for (int r = 0; r < 4; ++r) {
            wkfr[t][r] = Wk[colb + r];
            bfr[t][r]  = bv[colb + r];
        }
    }
}

// One LSTM step; h enters/exits in MFMA B-frag layout (identity recurrence).
// Transcendental-shared activations: i*g and o*tanh(c) each use ONE rcp.
__device__ __forceinline__ void lstm_step3(float x,
    const bf16x8* Ahi, const bf16x8* Alo,
    const f32x4* wkfr, const f32x4* bfr,
    bf16x8& h_hi, bf16x8& h_lo, f32x2* c2, f32x2* hv2) {
    f32x4 acc[8];
#pragma unroll
    for (int t = 0; t < 8; ++t) {
        f32x4 a;
#pragma unroll
        for (int r = 0; r < 4; ++r) a[r] = __builtin_fmaf(x, wkfr[t][r], bfr[t][r]);
        a = __builtin_amdgcn_mfma_f32_16x16x32_bf16(Alo[t], h_hi, a, 0, 0, 0);
        a = __builtin_amdgcn_mfma_f32_16x16x32_bf16(Ahi[t], h_lo, a, 0, 0, 0);
        a = __builtin_amdgcn_mfma_f32_16x16x32_bf16(Ahi[t], h_hi, a, 0, 0, 0);
        acc[t] = a;
    }
    const f32x2 one = {1.0f, 1.0f};
    const f32x2 k1 = {-L2E, -L2E};
    const f32x2 k2 = {-2.0f * L2E, -2.0f * L2E};
    u32x4 hh_u, hl_u;
#pragma unroll
    for (int tl = 0; tl < 2; ++tl) {
#pragma unroll
        for (int rp = 0; rp < 2; ++rp) {
            const int r0 = 2 * rp;
            const int p = tl * 2 + rp;
            f32x2 zi = {acc[0 + tl][r0], acc[0 + tl][r0 + 1]};
            f32x2 zf = {acc[2 + tl][r0], acc[2 + tl][r0 + 1]};
            f32x2 zg = {acc[4 + tl][r0], acc[4 + tl][r0 + 1]};
            f32x2 zo = {acc[6 + tl][r0], acc[6 + tl][r0 + 1]};
            f32x2 e_i = exp2v(zi * k1);                  // e^-zi
            f32x2 e_f = exp2v(zf * k1);
            f32x2 e_g = exp2v(minv(zg * k2, 64.0f));     // e^-2zg (clamped)
            f32x2 e_o = exp2v(zo * k1);
            f32x2 fg = rcpv(one + e_f);                  // sigmoid(zf)
            f32x2 ig = (one - e_g) * rcpv((one + e_i) * (one + e_g));  // sig(zi)*tanh(zg)
            f32x2 cn = fg * c2[p] + ig;
            c2[p] = cn;
            f32x2 e_c = exp2v(minv(cn * k2, 64.0f));     // e^-2cn (clamped)
            f32x2 h = (one - e_c) * rcpv((one + e_o) * (one + e_c));   // sig(zo)*tanh(cn)
            hv2[p] = h;
            unsigned uh, ul;
            bf_split_pair(h.x, h.y, uh, ul);
            hh_u[p] = uh; hl_u[p] = ul;
        }
    }
    h_hi = __builtin_bit_cast(bf16x8, hh_u);
    h_lo = __builtin_bit_cast(bf16x8, hl_u);
}

__global__ __launch_bounds__(256, 4) void lstm_feedback_mfma3(
    const float* __restrict__ inputs,  // [B, 48]
    const float* __restrict__ Wk_w, const float* __restrict__ Uk_w, const float* __restrict__ b_w,
    const float* __restrict__ Wk_d, const float* __restrict__ Uk_d, const float* __restrict__ b_d,
    const float* __restrict__ Wd, const float* __restrict__ bd,
    float* __restrict__ out,           // [B, 24]
    int B) {
    const int tid = threadIdx.x;       // 256 threads = 4 independent waves
    const int w = tid >> 6;
    const int lane = tid & 63;
    const int LQ = lane >> 4;
    const int LC = lane & 15;          // this lane's batch column within the wave
    const int mblk = blockIdx.x * 64;  // block's 64 batch rows

    __shared__ float xbuf[4][16 * 49];    // stride 49: conflict-free column reads
    __shared__ float predbuf[4][16 * 25]; // stride 25: conflict-free scattered writes

    // Whole block cooperatively loads its 64x48 input tile (coalesced).
    for (int i = tid; i < 64 * TSTEPS; i += 256) {
        int m = i / TSTEPS, t = i - m * TSTEPS;
        xbuf[m >> 4][(m & 15) * 49 + t] = inputs[(long)mblk * TSTEPS + i];
    }

    bf16x8 Ahi[8], Alo[8];
    f32x4 wkfr[8], bfr[8];
    load_weights(Uk_w, Wk_w, b_w, Ahi, Alo, wkfr, bfr, LQ, LC);

    bf16x8 h_hi = {0, 0, 0, 0, 0, 0, 0, 0};
    bf16x8 h_lo = {0, 0, 0, 0, 0, 0, 0, 0};
    f32x2 c2[4] = {{0, 0}, {0, 0}, {0, 0}, {0, 0}};
    f32x2 hv2[4];

    f32x2 wdv2[4];
#pragma unroll
    for (int p2 = 0; p2 < 4; ++p2)
        wdv2[p2] = (f32x2){Wd[LQ * 8 + 2 * p2], Wd[LQ * 8 + 2 * p2 + 1]};
    const float bdv = bd[0];

    __syncthreads();  // xbuf visible

    const float* __restrict__ xcol = &xbuf[w][LC * 49];

    // ---- warmup: 48 steps, no LDS/barriers inside ----
    for (int t = 0; t < TSTEPS; ++t) {
        lstm_step3(xcol[t], Ahi, Alo, wkfr, bfr, h_hi, h_lo, c2, hv2);
    }

    // ---- first prediction: partial dot + 2-shuffle butterfly ----
    f32x2 ps = hv2[0] * wdv2[0];
#pragma unroll
    for (int p2 = 1; p2 < 4; ++p2) ps += hv2[p2] * wdv2[p2];
    float p = ps.x + ps.y;
    p += __shfl_xor(p, 16);
    p += __shfl_xor(p, 32);
    p += bdv;                          // all lanes of column LC hold pred(batch LC)
    if (LQ == 0) predbuf[w][LC * 25 + 0] = p;

    // ---- decode weights ----
    load_weights(Uk_d, Wk_d, b_d, Ahi, Alo, wkfr, bfr, LQ, LC);

    for (int s = 1; s < OUT_STEPS; ++s) {
        lstm_step3(p, Ahi, Alo, wkfr, bfr, h_hi, h_lo, c2, hv2);
        ps = hv2[0] * wdv2[0];
#pragma unroll
        for (int p2 = 1; p2 < 4; ++p2) ps += hv2[p2] * wdv2[p2];
        p = ps.x + ps.y;
        p += __shfl_xor(p, 16);
        p += __shfl_xor(p, 32);
        p += bdv;
        if (LQ == 0) predbuf[w][LC * 25 + s] = p;
    }

    // ---- coalesced output flush ----
    __syncthreads();
    for (int i = tid; i < 64 * OUT_STEPS; i += 256) {
        int m = i / OUT_STEPS, s = i - m * OUT_STEPS;
        out[(long)mblk * OUT_STEPS + i] = predbuf[m >> 4][(m & 15) * 25 + s];
    }
}

extern "C" void kernel_launch(void* const* d_in, const int* in_sizes, int n_in,
                              void* d_out, int out_size, void* d_ws, size_t ws_size,
                              hipStream_t stream) {
    const float* inputs = (const float*)d_in[0];
    const float* Wk_w   = (const float*)d_in[1];
    const float* Uk_w   = (const float*)d_in[2];
    const float* b_w    = (const float*)d_in[3];
    const float* Wk_d   = (const float*)d_in[4];
    const float* Uk_d   = (const float*)d_in[5];
    const float* b_d    = (const float*)d_in[6];
    const float* Wd     = (const float*)d_in[7];
    const float* bd     = (const float*)d_in[8];
    float* out = (float*)d_out;

    const int B = in_sizes[0] / TSTEPS;
    const int grid = (B + 63) / 64;   // 64 batch rows per 256-thread block
    lstm_feedback_mfma3<<<grid, 256, 0, stream>>>(
        inputs, Wk_w, Uk_w, b_w, Wk_d, Uk_d, b_d, Wd, bd, out, B);
}

// Round 5
// 444.039 us; speedup vs baseline: 3.0313x; 3.0313x over previous
//
#include <hip/hip_runtime.h>

#define TSTEPS 48
#define OUT_STEPS 24

typedef __attribute__((ext_vector_type(8))) short bf16x8;
typedef __attribute__((ext_vector_type(4))) float f32x4;
typedef __attribute__((ext_vector_type(2))) float f32x2;
typedef __attribute__((ext_vector_type(4))) unsigned int u32x4;

#define L2E 1.44269504088896340736f

__device__ __forceinline__ f32x2 exp2v(f32x2 a) {
    return (f32x2){__builtin_amdgcn_exp2f(a.x), __builtin_amdgcn_exp2f(a.y)};
}
__device__ __forceinline__ f32x2 rcpv(f32x2 a) {
    return (f32x2){__builtin_amdgcn_rcpf(a.x), __builtin_amdgcn_rcpf(a.y)};
}
__device__ __forceinline__ f32x2 minv(f32x2 a, float m) {
    return (f32x2){__builtin_fminf(a.x, m), __builtin_fminf(a.y, m)};
}

// RNE hi/lo split (weights only; off the hot path).
__device__ __forceinline__ void bf_split(float f, short& hi, short& lo) {
    unsigned u = __builtin_bit_cast(unsigned, f);
    unsigned r = u + 0x7FFFu + ((u >> 16) & 1u);
    unsigned short hb = (unsigned short)(r >> 16);
    float hif = __builtin_bit_cast(float, (unsigned)hb << 16);
    float lof = f - hif;
    unsigned short lb = (unsigned short)(__builtin_bit_cast(unsigned, lof) >> 16);
    hi = (short)hb; lo = (short)lb;
}

// Truncation split of a PAIR, packed to dwords (low half = first value).
// hi error captured exactly by lo; residual ~2^-17 relative.
__device__ __forceinline__ void bf_split_pair(float f0, float f1,
                                              unsigned& hi, unsigned& lo) {
    unsigned u0 = __builtin_bit_cast(unsigned, f0);
    unsigned u1 = __builtin_bit_cast(unsigned, f1);
    hi = __builtin_amdgcn_perm(u1, u0, 0x07060302u);  // [u0.hi16, u1.hi16]
    float h0 = __builtin_bit_cast(float, u0 & 0xFFFF0000u);
    float h1 = __builtin_bit_cast(float, u1 & 0xFFFF0000u);
    float l0 = f0 - h0, l1 = f1 - h1;
    unsigned v0 = __builtin_bit_cast(unsigned, l0);
    unsigned v1 = __builtin_bit_cast(unsigned, l1);
    lo = __builtin_amdgcn_perm(v1, v0, 0x07060302u);
}

// A-fragments of permuted U^T (hi/lo split) + per-lane Wk/b constants in D order.
// Row permutation: row R=16t+rho <-> gate=(t>>1), unit u=(rho>>2)*8+(t&1)*4+(rho&3).
__device__ __forceinline__ void load_weights(const float* __restrict__ Uk,
                                             const float* __restrict__ Wk,
                                             const float* __restrict__ bv,
                                             bf16x8* Ahi, bf16x8* Alo,
                                             f32x4* wkfr, f32x4* bfr, int LQ, int LC) {
    const int ulo = ((LC >> 2) << 3) + (LC & 3);
#pragma unroll
    for (int t = 0; t < 8; ++t) {
        const int col = (t >> 1) * 32 + ulo + (t & 1) * 4;
        bf16x8 ah, al;
#pragma unroll
        for (int j = 0; j < 8; ++j) {
            float w = Uk[(LQ * 8 + j) * 128 + col];
            short hb, lb; bf_split(w, hb, lb);
            ah[j] = hb; al[j] = lb;
        }
        Ahi[t] = ah; Alo[t] = al;
        const int colb = (t >> 1) * 32 + LQ * 8 + (t & 1) * 4;
#pragma unroll
        for (int r = 0; r < 4; ++r) {
            wkfr[t][r] = Wk[colb + r];
            bfr[t][r]  = bv[colb + r];
        }
    }
}

// One LSTM step; h enters/exits in MFMA B-frag layout (identity recurrence).
// Transcendental-shared activations: i*g and o*tanh(c) each use ONE rcp.
__device__ __forceinline__ void lstm_step3(float x,
    const bf16x8* Ahi, const bf16x8* Alo,
    const f32x4* wkfr, const f32x4* bfr,
    bf16x8& h_hi, bf16x8& h_lo, f32x2* c2, f32x2* hv2) {
    f32x4 acc[8];
#pragma unroll
    for (int t = 0; t < 8; ++t) {
        f32x4 a;
#pragma unroll
        for (int r = 0; r < 4; ++r) a[r] = __builtin_fmaf(x, wkfr[t][r], bfr[t][r]);
        a = __builtin_amdgcn_mfma_f32_16x16x32_bf16(Alo[t], h_hi, a, 0, 0, 0);
        a = __builtin_amdgcn_mfma_f32_16x16x32_bf16(Ahi[t], h_lo, a, 0, 0, 0);
        a = __builtin_amdgcn_mfma_f32_16x16x32_bf16(Ahi[t], h_hi, a, 0, 0, 0);
        acc[t] = a;
    }
    const f32x2 one = {1.0f, 1.0f};
    const f32x2 k1 = {-L2E, -L2E};
    const f32x2 k2 = {-2.0f * L2E, -2.0f * L2E};
    u32x4 hh_u, hl_u;
#pragma unroll
    for (int tl = 0; tl < 2; ++tl) {
#pragma unroll
        for (int rp = 0; rp < 2; ++rp) {
            const int r0 = 2 * rp;
            const int p = tl * 2 + rp;
            f32x2 zi = {acc[0 + tl][r0], acc[0 + tl][r0 + 1]};
            f32x2 zf = {acc[2 + tl][r0], acc[2 + tl][r0 + 1]};
            f32x2 zg = {acc[4 + tl][r0], acc[4 + tl][r0 + 1]};
            f32x2 zo = {acc[6 + tl][r0], acc[6 + tl][r0 + 1]};
            f32x2 e_i = exp2v(zi * k1);                  // e^-zi
            f32x2 e_f = exp2v(zf * k1);
            f32x2 e_g = exp2v(minv(zg * k2, 64.0f));     // e^-2zg (clamped)
            f32x2 e_o = exp2v(zo * k1);
            f32x2 fg = rcpv(one + e_f);                  // sigmoid(zf)
            f32x2 ig = (one - e_g) * rcpv((one + e_i) * (one + e_g));  // sig(zi)*tanh(zg)
            f32x2 cn = fg * c2[p] + ig;
            c2[p] = cn;
            f32x2 e_c = exp2v(minv(cn * k2, 64.0f));     // e^-2cn (clamped)
            f32x2 h = (one - e_c) * rcpv((one + e_o) * (one + e_c));   // sig(zo)*tanh(cn)
            hv2[p] = h;
            unsigned uh, ul;
            bf_split_pair(h.x, h.y, uh, ul);
            hh_u[p] = uh; hl_u[p] = ul;
        }
    }
    h_hi = __builtin_bit_cast(bf16x8, hh_u);
    h_lo = __builtin_bit_cast(bf16x8, hl_u);
}

// launch_bounds(256, 2): VGPR cap 256. R4's (256,4) clamped VGPR to 64 ->
// scratch spills in the hot loop -> 4.9 GB HBM traffic. Natural allocation
// ~116-140 VGPR gives 4 waves/SIMD anyway (cap at 128 happens by fitting,
// not forcing).
__global__ __launch_bounds__(256, 2) void lstm_feedback_mfma4(
    const float* __restrict__ inputs,  // [B, 48]
    const float* __restrict__ Wk_w, const float* __restrict__ Uk_w, const float* __restrict__ b_w,
    const float* __restrict__ Wk_d, const float* __restrict__ Uk_d, const float* __restrict__ b_d,
    const float* __restrict__ Wd, const float* __restrict__ bd,
    float* __restrict__ out,           // [B, 24]
    int B) {
    const int tid = threadIdx.x;       // 256 threads = 4 independent waves
    const int w = tid >> 6;
    const int lane = tid & 63;
    const int LQ = lane >> 4;
    const int LC = lane & 15;          // this lane's batch column within the wave
    const int mblk = blockIdx.x * 64;  // block's 64 batch rows

    __shared__ float xbuf[4][16 * 49];    // stride 49: conflict-free column reads
    __shared__ float predbuf[4][16 * 25]; // stride 25: conflict-free scattered writes

    // Whole block cooperatively loads its 64x48 input tile (coalesced).
    for (int i = tid; i < 64 * TSTEPS; i += 256) {
        int m = i / TSTEPS, t = i - m * TSTEPS;
        xbuf[m >> 4][(m & 15) * 49 + t] = inputs[(long)mblk * TSTEPS + i];
    }

    bf16x8 Ahi[8], Alo[8];
    f32x4 wkfr[8], bfr[8];
    load_weights(Uk_w, Wk_w, b_w, Ahi, Alo, wkfr, bfr, LQ, LC);

    bf16x8 h_hi = {0, 0, 0, 0, 0, 0, 0, 0};
    bf16x8 h_lo = {0, 0, 0, 0, 0, 0, 0, 0};
    f32x2 c2[4] = {{0, 0}, {0, 0}, {0, 0}, {0, 0}};
    f32x2 hv2[4];

    f32x2 wdv2[4];
#pragma unroll
    for (int p2 = 0; p2 < 4; ++p2)
        wdv2[p2] = (f32x2){Wd[LQ * 8 + 2 * p2], Wd[LQ * 8 + 2 * p2 + 1]};
    const float bdv = bd[0];

    __syncthreads();  // xbuf visible

    const float* __restrict__ xcol = &xbuf[w][LC * 49];

    // ---- warmup: 48 steps, no LDS/barriers inside ----
    for (int t = 0; t < TSTEPS; ++t) {
        lstm_step3(xcol[t], Ahi, Alo, wkfr, bfr, h_hi, h_lo, c2, hv2);
    }

    // ---- first prediction: partial dot + 2-shuffle butterfly ----
    f32x2 ps = hv2[0] * wdv2[0];
#pragma unroll
    for (int p2 = 1; p2 < 4; ++p2) ps += hv2[p2] * wdv2[p2];
    float p = ps.x + ps.y;
    p += __shfl_xor(p, 16);
    p += __shfl_xor(p, 32);
    p += bdv;                          // all lanes of column LC hold pred(batch LC)
    if (LQ == 0) predbuf[w][LC * 25 + 0] = p;

    // ---- decode weights ----
    load_weights(Uk_d, Wk_d, b_d, Ahi, Alo, wkfr, bfr, LQ, LC);

    for (int s = 1; s < OUT_STEPS; ++s) {
        lstm_step3(p, Ahi, Alo, wkfr, bfr, h_hi, h_lo, c2, hv2);
        ps = hv2[0] * wdv2[0];
#pragma unroll
        for (int p2 = 1; p2 < 4; ++p2) ps += hv2[p2] * wdv2[p2];
        p = ps.x + ps.y;
        p += __shfl_xor(p, 16);
        p += __shfl_xor(p, 32);
        p += bdv;
        if (LQ == 0) predbuf[w][LC * 25 + s] = p;
    }

    // ---- coalesced output flush ----
    __syncthreads();
    for (int i = tid; i < 64 * OUT_STEPS; i += 256) {
        int m = i / OUT_STEPS, s = i - m * OUT_STEPS;
        out[(long)mblk * OUT_STEPS + i] = predbuf[m >> 4][(m & 15) * 25 + s];
    }
}

extern "C" void kernel_launch(void* const* d_in, const int* in_sizes, int n_in,
                              void* d_out, int out_size, void* d_ws, size_t ws_size,
                              hipStream_t stream) {
    const float* inputs = (const float*)d_in[0];
    const float* Wk_w   = (const float*)d_in[1];
    const float* Uk_w   = (const float*)d_in[2];
    const float* b_w    = (const float*)d_in[3];
    const float* Wk_d   = (const float*)d_in[4];
    const float* Uk_d   = (const float*)d_in[5];
    const float* b_d    = (const float*)d_in[6];
    const float* Wd     = (const float*)d_in[7];
    const float* bd     = (const float*)d_in[8];
    float* out = (float*)d_out;

    const int B = in_sizes[0] / TSTEPS;
    const int grid = (B + 63) / 64;   // 64 batch rows per 256-thread block
    lstm_feedback_mfma4<<<grid, 256, 0, stream>>>(
        inputs, Wk_w, Uk_w, b_w, Wk_d, Uk_d, b_d, Wd, bd, out, B);
}